// Round 1
// baseline (298.765 us; speedup 1.0000x reference)
//
#include <hip/hip_runtime.h>
#include <hip/hip_bf16.h>

#define NB 16
#define NT 2048
#define NDM 1024
#define NDK 128

typedef __bf16 bf16;
typedef bf16 bf16x4 __attribute__((ext_vector_type(4)));
typedef bf16 bf16x8 __attribute__((ext_vector_type(8)));
typedef float f32x4 __attribute__((ext_vector_type(4)));

__device__ inline bf16 to_bf16(float f) {
    __hip_bfloat16 h = __float2bfloat16(f);
    return *reinterpret_cast<bf16*>(&h);
}

// ---------------------------------------------------------------------------
// Kernel 1: W [1024][128] f32  ->  Wt bf16 [3][128][1024]  (transposed, K-major)
// ---------------------------------------------------------------------------
__global__ __launch_bounds__(256) void transpose_w_kernel(
        const float* __restrict__ Wq, const float* __restrict__ Wk,
        const float* __restrict__ Wv, bf16* __restrict__ Wt) {
    int idx = blockIdx.x * 256 + threadIdx.x;      // over 3*1024*128
    int w = idx >> 17;                             // / (1024*128)
    int r = idx & (NDM * NDK - 1);
    int k = r >> 7;                                // / 128
    int n = r & (NDK - 1);
    const float* W = (w == 0) ? Wq : ((w == 1) ? Wk : Wv);
    Wt[(size_t)w * NDK * NDM + (size_t)n * NDM + k] = to_bf16(W[(size_t)k * NDK + n]);
}

// ---------------------------------------------------------------------------
// Kernel 2: QKV projection. x[f32, M=B*T x 1024] @ Wt^T -> qkv bf16 [3][M][128]
// Tile: BM=128, BN=128, BK=32. 4 waves in 2x2, each 64x64 (4x4 MFMA frags).
// ---------------------------------------------------------------------------
__global__ __launch_bounds__(256) void proj_kernel(
        const float* __restrict__ x, const bf16* __restrict__ Wt,
        bf16* __restrict__ qkv) {
    __shared__ bf16 As[128][32];
    __shared__ bf16 Bs[128][32];   // [n][k]
    const int tid = threadIdx.x;
    const int lane = tid & 63;
    const int wave = tid >> 6;
    const int wr = wave >> 1, wc = wave & 1;
    const int r16 = lane & 15, kg = lane >> 4;
    const int mb = blockIdx.x;
    const int w = blockIdx.y;
    const float* xA = x + (size_t)mb * 128 * NDM;
    const bf16* Bt = Wt + (size_t)w * NDK * NDM;

    f32x4 acc[4][4];
#pragma unroll
    for (int m = 0; m < 4; m++)
#pragma unroll
        for (int n = 0; n < 4; n++) acc[m][n] = (f32x4){0.f, 0.f, 0.f, 0.f};

    for (int k0 = 0; k0 < NDM; k0 += 32) {
        // stage A: 128x32 f32 -> bf16
#pragma unroll
        for (int p = 0; p < 4; p++) {
            int row = p * 32 + (tid >> 3);
            int c4 = (tid & 7) * 4;
            const float4 v = *reinterpret_cast<const float4*>(&xA[(size_t)row * NDM + k0 + c4]);
            bf16x4 bv = { to_bf16(v.x), to_bf16(v.y), to_bf16(v.z), to_bf16(v.w) };
            *reinterpret_cast<bf16x4*>(&As[row][c4]) = bv;
        }
        // stage B: 128x32 bf16 (already K-contiguous)
#pragma unroll
        for (int p = 0; p < 2; p++) {
            int idx = (p * 256 + tid) * 8;
            int n = idx >> 5;
            int kk = idx & 31;
            *reinterpret_cast<bf16x8*>(&Bs[n][kk]) =
                *reinterpret_cast<const bf16x8*>(&Bt[(size_t)n * NDM + k0 + kk]);
        }
        __syncthreads();
        bf16x8 af[4], bfr[4];
#pragma unroll
        for (int m = 0; m < 4; m++)
            af[m] = *reinterpret_cast<const bf16x8*>(&As[wr * 64 + m * 16 + r16][kg * 8]);
#pragma unroll
        for (int n = 0; n < 4; n++)
            bfr[n] = *reinterpret_cast<const bf16x8*>(&Bs[wc * 64 + n * 16 + r16][kg * 8]);
#pragma unroll
        for (int m = 0; m < 4; m++)
#pragma unroll
            for (int n = 0; n < 4; n++)
                acc[m][n] = __builtin_amdgcn_mfma_f32_16x16x32_bf16(af[m], bfr[n], acc[m][n], 0, 0, 0);
        __syncthreads();
    }

    bf16* outw = qkv + (size_t)w * (size_t)(NB * NT) * NDK;
#pragma unroll
    for (int m = 0; m < 4; m++) {
        int rowb = mb * 128 + wr * 64 + m * 16 + kg * 4;
#pragma unroll
        for (int n = 0; n < 4; n++) {
            int col = wc * 64 + n * 16 + r16;
#pragma unroll
            for (int r = 0; r < 4; r++)
                outw[(size_t)(rowb + r) * NDK + col] = to_bf16(acc[m][n][r]);
        }
    }
}

// ---------------------------------------------------------------------------
// Kernel 3: causal flash attention. Q,K,V bf16 [B][T][128] -> out f32.
// Block: 64 q-rows, 4 waves x 16 rows. KV tile = 64.
// ---------------------------------------------------------------------------
__global__ __launch_bounds__(256) void attn_kernel(
        const bf16* __restrict__ Q, const bf16* __restrict__ K,
        const bf16* __restrict__ V, float* __restrict__ out) {
    __shared__ bf16 Ks[64][128];   // K rows (== B-operand of QK^T, K-contiguous)
    __shared__ bf16 Vt[128][72];   // V transposed [d][kv], padded
    __shared__ bf16 Ps[4][16][64]; // per-wave P relayout buffer
    const int tid = threadIdx.x, lane = tid & 63, wave = tid >> 6;
    const int r16 = lane & 15, kg = lane >> 4;
    const int qb = blockIdx.x, b = blockIdx.y;
    const int q0 = qb * 64;
    const size_t baseB = (size_t)b * NT * NDK;

    // Q fragments (A-operand), 16 rows per wave, full DK=128
    bf16x8 qf[4];
    const int qrow = q0 + wave * 16 + r16;
#pragma unroll
    for (int kc = 0; kc < 4; kc++)
        qf[kc] = *reinterpret_cast<const bf16x8*>(&Q[baseB + (size_t)qrow * NDK + kc * 32 + kg * 8]);

    f32x4 o[8];
#pragma unroll
    for (int n = 0; n < 8; n++) o[n] = (f32x4){0.f, 0.f, 0.f, 0.f};
    float mrow[4] = {-INFINITY, -INFINITY, -INFINITY, -INFINITY};
    float lrow[4] = {0.f, 0.f, 0.f, 0.f};
    const float scale = 0.08838834764831843f;  // 1/sqrt(128)

    const int nsteps = qb + 1;
    for (int s = 0; s < nsteps; s++) {
        const int kv0 = s * 64;
        // stage K tile [64][128]
#pragma unroll
        for (int i = 0; i < 4; i++) {
            int idx = (i * 256 + tid) * 8;
            int row = idx >> 7, col = idx & 127;
            *reinterpret_cast<bf16x8*>(&Ks[row][col]) =
                *reinterpret_cast<const bf16x8*>(&K[baseB + (size_t)(kv0 + row) * NDK + col]);
        }
        // stage V transposed -> Vt[d][kv]
#pragma unroll
        for (int i = 0; i < 4; i++) {
            int idx = (i * 256 + tid) * 8;
            int row = idx >> 7, col = idx & 127;
            bf16x8 v = *reinterpret_cast<const bf16x8*>(&V[baseB + (size_t)(kv0 + row) * NDK + col]);
#pragma unroll
            for (int j = 0; j < 8; j++) Vt[col + j][row] = v[j];
        }
        __syncthreads();

        // S = Q K^T  (4 kv-col tiles x 4 k-chunks)
        f32x4 sfr[4];
#pragma unroll
        for (int n = 0; n < 4; n++) sfr[n] = (f32x4){0.f, 0.f, 0.f, 0.f};
#pragma unroll
        for (int n = 0; n < 4; n++) {
#pragma unroll
            for (int kc = 0; kc < 4; kc++) {
                bf16x8 kf = *reinterpret_cast<const bf16x8*>(&Ks[n * 16 + r16][kc * 32 + kg * 8]);
                sfr[n] = __builtin_amdgcn_mfma_f32_16x16x32_bf16(qf[kc], kf, sfr[n], 0, 0, 0);
            }
        }

        // scale + causal mask + row max
        float pmax[4] = {-INFINITY, -INFINITY, -INFINITY, -INFINITY};
#pragma unroll
        for (int n = 0; n < 4; n++) {
#pragma unroll
            for (int r = 0; r < 4; r++) {
                float sv = sfr[n][r] * scale;
                int col = kv0 + n * 16 + r16;
                int row = q0 + wave * 16 + kg * 4 + r;
                if (col > row) sv = -INFINITY;
                sfr[n][r] = sv;
                pmax[r] = fmaxf(pmax[r], sv);
            }
        }
#pragma unroll
        for (int d = 1; d < 16; d <<= 1)
#pragma unroll
            for (int r = 0; r < 4; r++)
                pmax[r] = fmaxf(pmax[r], __shfl_xor(pmax[r], d, 64));

        float mnew[4], corr[4];
#pragma unroll
        for (int r = 0; r < 4; r++) {
            mnew[r] = fmaxf(mrow[r], pmax[r]);
            corr[r] = __expf(mrow[r] - mnew[r]);
            mrow[r] = mnew[r];
        }

        // P = exp(s - m), row sums, stash to LDS for relayout
        float psum[4] = {0.f, 0.f, 0.f, 0.f};
#pragma unroll
        for (int n = 0; n < 4; n++) {
#pragma unroll
            for (int r = 0; r < 4; r++) {
                float pv = __expf(sfr[n][r] - mnew[r]);
                psum[r] += pv;
                Ps[wave][kg * 4 + r][n * 16 + r16] = to_bf16(pv);
            }
        }
#pragma unroll
        for (int d = 1; d < 16; d <<= 1)
#pragma unroll
            for (int r = 0; r < 4; r++)
                psum[r] += __shfl_xor(psum[r], d, 64);
#pragma unroll
        for (int r = 0; r < 4; r++) lrow[r] = lrow[r] * corr[r] + psum[r];
#pragma unroll
        for (int n = 0; n < 8; n++)
#pragma unroll
            for (int r = 0; r < 4; r++) o[n][r] *= corr[r];

        // O += P V   (P as A-operand from Ps, V^T as B-operand from Vt)
#pragma unroll
        for (int kc2 = 0; kc2 < 2; kc2++) {
            bf16x8 pf = *reinterpret_cast<const bf16x8*>(&Ps[wave][r16][kc2 * 32 + kg * 8]);
#pragma unroll
            for (int n = 0; n < 8; n++) {
                bf16x8 vf = *reinterpret_cast<const bf16x8*>(&Vt[n * 16 + r16][kc2 * 32 + kg * 8]);
                o[n] = __builtin_amdgcn_mfma_f32_16x16x32_bf16(pf, vf, o[n], 0, 0, 0);
            }
        }
        __syncthreads();
    }

    float inv[4];
#pragma unroll
    for (int r = 0; r < 4; r++) inv[r] = 1.0f / lrow[r];
#pragma unroll
    for (int n = 0; n < 8; n++)
#pragma unroll
        for (int r = 0; r < 4; r++) {
            int row = q0 + wave * 16 + kg * 4 + r;
            int col = n * 16 + r16;
            out[baseB + (size_t)row * NDK + col] = o[n][r] * inv[r];
        }
}

// ---------------------------------------------------------------------------
extern "C" void kernel_launch(void* const* d_in, const int* in_sizes, int n_in,
                              void* d_out, int out_size, void* d_ws, size_t ws_size,
                              hipStream_t stream) {
    const float* x  = (const float*)d_in[0];
    const float* Wq = (const float*)d_in[1];
    const float* Wk = (const float*)d_in[2];
    const float* Wv = (const float*)d_in[3];
    float* out = (float*)d_out;

    char* ws = (char*)d_ws;
    bf16* Wt  = (bf16*)ws;                       // 3*128*1024*2  = 768 KB
    bf16* qkv = (bf16*)(ws + (1 << 20));         // 3*16*2048*128*2 = 24 MB

    // 1) transpose weights to bf16 [3][128][1024]
    transpose_w_kernel<<<(3 * NDM * NDK) / 256, 256, 0, stream>>>(Wq, Wk, Wv, Wt);

    // 2) QKV projection
    dim3 g1((NB * NT) / 128, 3);
    proj_kernel<<<g1, 256, 0, stream>>>(x, Wt, qkv);

    // 3) causal flash attention
    bf16* Qp = qkv;
    bf16* Kp = qkv + (size_t)(NB * NT) * NDK;
    bf16* Vp = qkv + 2 * (size_t)(NB * NT) * NDK;
    dim3 g2(NT / 64, NB);
    attn_kernel<<<g2, 256, 0, stream>>>(Qp, Kp, Vp, out);
}

// Round 2
// 194.600 us; speedup vs baseline: 1.5353x; 1.5353x over previous
//
#include <hip/hip_runtime.h>
#include <hip/hip_bf16.h>

#define NB 16
#define NT 2048
#define NDM 1024
#define NDK 128

typedef __bf16 bf16;
typedef bf16 bf16x4 __attribute__((ext_vector_type(4)));
typedef bf16 bf16x8 __attribute__((ext_vector_type(8)));
typedef float f32x4 __attribute__((ext_vector_type(4)));

__device__ inline bf16 to_bf16(float f) {
    __hip_bfloat16 h = __float2bfloat16(f);
    return *reinterpret_cast<bf16*>(&h);
}

// ---------------------------------------------------------------------------
// Kernel 1: W [1024][128] f32  ->  Wt bf16 [3][128][1024]  (transposed, K-major)
// ---------------------------------------------------------------------------
__global__ __launch_bounds__(256) void transpose_w_kernel(
        const float* __restrict__ Wq, const float* __restrict__ Wk,
        const float* __restrict__ Wv, bf16* __restrict__ Wt) {
    int idx = blockIdx.x * 256 + threadIdx.x;      // over 3*1024*128
    int w = idx >> 17;                             // / (1024*128)
    int r = idx & (NDM * NDK - 1);
    int k = r >> 7;                                // / 128
    int n = r & (NDK - 1);
    const float* W = (w == 0) ? Wq : ((w == 1) ? Wk : Wv);
    Wt[(size_t)w * NDK * NDM + (size_t)n * NDM + k] = to_bf16(W[(size_t)k * NDK + n]);
}

// ---------------------------------------------------------------------------
// Kernel 2: QKV projection. x[f32, M=B*T x 1024] @ Wt^T -> qkv bf16 [3][M][128]
// Tile: BM=128, BN=128, BK=32. 4 waves in 2x2, each 64x64 (4x4 MFMA frags).
// LDS rows padded to 40 bf16 (80 B) -> read conflicts ~2-way instead of 8-way.
// ---------------------------------------------------------------------------
__global__ __launch_bounds__(256) void proj_kernel(
        const float* __restrict__ x, const bf16* __restrict__ Wt,
        bf16* __restrict__ qkv) {
    __shared__ bf16 As[128][40];
    __shared__ bf16 Bs[128][40];   // [n][k]
    const int tid = threadIdx.x;
    const int lane = tid & 63;
    const int wave = tid >> 6;
    const int wr = wave >> 1, wc = wave & 1;
    const int r16 = lane & 15, kg = lane >> 4;
    const int mb = blockIdx.x;
    const int w = blockIdx.y;
    const float* xA = x + (size_t)mb * 128 * NDM;
    const bf16* Bt = Wt + (size_t)w * NDK * NDM;

    f32x4 acc[4][4];
#pragma unroll
    for (int m = 0; m < 4; m++)
#pragma unroll
        for (int n = 0; n < 4; n++) acc[m][n] = (f32x4){0.f, 0.f, 0.f, 0.f};

    for (int k0 = 0; k0 < NDM; k0 += 32) {
        // stage A: 128x32 f32 -> bf16
#pragma unroll
        for (int p = 0; p < 4; p++) {
            int row = p * 32 + (tid >> 3);
            int c4 = (tid & 7) * 4;
            const float4 v = *reinterpret_cast<const float4*>(&xA[(size_t)row * NDM + k0 + c4]);
            bf16x4 bv = { to_bf16(v.x), to_bf16(v.y), to_bf16(v.z), to_bf16(v.w) };
            *reinterpret_cast<bf16x4*>(&As[row][c4]) = bv;
        }
        // stage B: 128x32 bf16 (already K-contiguous)
#pragma unroll
        for (int p = 0; p < 2; p++) {
            int idx = (p * 256 + tid) * 8;
            int n = idx >> 5;
            int kk = idx & 31;
            *reinterpret_cast<bf16x8*>(&Bs[n][kk]) =
                *reinterpret_cast<const bf16x8*>(&Bt[(size_t)n * NDM + k0 + kk]);
        }
        __syncthreads();
        bf16x8 af[4], bfr[4];
#pragma unroll
        for (int m = 0; m < 4; m++)
            af[m] = *reinterpret_cast<const bf16x8*>(&As[wr * 64 + m * 16 + r16][kg * 8]);
#pragma unroll
        for (int n = 0; n < 4; n++)
            bfr[n] = *reinterpret_cast<const bf16x8*>(&Bs[wc * 64 + n * 16 + r16][kg * 8]);
#pragma unroll
        for (int m = 0; m < 4; m++)
#pragma unroll
            for (int n = 0; n < 4; n++)
                acc[m][n] = __builtin_amdgcn_mfma_f32_16x16x32_bf16(af[m], bfr[n], acc[m][n], 0, 0, 0);
        __syncthreads();
    }

    bf16* outw = qkv + (size_t)w * (size_t)(NB * NT) * NDK;
#pragma unroll
    for (int m = 0; m < 4; m++) {
        int rowb = mb * 128 + wr * 64 + m * 16 + kg * 4;
#pragma unroll
        for (int n = 0; n < 4; n++) {
            int col = wc * 64 + n * 16 + r16;
#pragma unroll
            for (int r = 0; r < 4; r++)
                outw[(size_t)(rowb + r) * NDK + col] = to_bf16(acc[m][n][r]);
        }
    }
}

// ---------------------------------------------------------------------------
// Kernel 2.5: V [B][T][128] bf16 -> Vt [B][128][T] bf16 (one-time transpose,
// so attn stages V coalesced instead of scatter-transposing every KV step)
// ---------------------------------------------------------------------------
__global__ __launch_bounds__(256) void transpose_v_kernel(
        const bf16* __restrict__ V, bf16* __restrict__ Vt) {
    __shared__ bf16 Tl[64][136];   // [t][d], padded
    const int tid = threadIdx.x;
    const int tb = blockIdx.x, b = blockIdx.y;
    const int t0 = tb * 64;
    const size_t ibase = (size_t)b * NT * NDK;
    const size_t obase = (size_t)b * NDK * NT;
#pragma unroll
    for (int p = 0; p < 4; p++) {
        int idx = p * 256 + tid;           // chunk over 64 rows x 16 chunks
        int row = idx >> 4, c = idx & 15;
        *reinterpret_cast<bf16x8*>(&Tl[row][c * 8]) =
            *reinterpret_cast<const bf16x8*>(&V[ibase + (size_t)(t0 + row) * NDK + c * 8]);
    }
    __syncthreads();
#pragma unroll
    for (int p = 0; p < 4; p++) {
        int idx = p * 256 + tid;           // chunk over 128 d-rows x 8 chunks
        int d = idx >> 3, c = idx & 7;
        bf16x8 v;
#pragma unroll
        for (int j = 0; j < 8; j++) v[j] = Tl[c * 8 + j][d];
        *reinterpret_cast<bf16x8*>(&Vt[obase + (size_t)d * NT + t0 + c * 8]) = v;
    }
}

// ---------------------------------------------------------------------------
// Kernel 3: causal flash attention. Q,K bf16 [B][T][128], Vt bf16 [B][128][T].
// Block: 64 q-rows, 4 waves x 16 rows. KV tile = 64.
// LDS tiles XOR-swizzled (16B chunk ^= row&7) -> conflict-free ds_read_b128.
// ---------------------------------------------------------------------------
__global__ __launch_bounds__(256) void attn_kernel(
        const bf16* __restrict__ Q, const bf16* __restrict__ K,
        const bf16* __restrict__ Vt, float* __restrict__ out) {
    __shared__ bf16 Ks[64][128];   // [kv][k], swizzled
    __shared__ bf16 Vs[128][64];   // [d][kv], swizzled
    __shared__ bf16 Ps[4][16][72]; // per-wave P relayout buffer (padded)
    const int tid = threadIdx.x, lane = tid & 63, wave = tid >> 6;
    const int r16 = lane & 15, kg = lane >> 4;
    const int qb = gridDim.x - 1 - blockIdx.x;   // longest blocks first
    const int b = blockIdx.y;
    const int q0 = qb * 64;
    const size_t baseB = (size_t)b * NT * NDK;
    const size_t baseVt = (size_t)b * NDK * NT;

    // Q fragments (A-operand), scale folded in; 16 rows per wave, DK=128
    const float scale = 0.08838834764831843f;  // 1/sqrt(128)
    bf16x8 qf[4];
    const int qrow = q0 + wave * 16 + r16;
#pragma unroll
    for (int kc = 0; kc < 4; kc++) {
        bf16x8 raw = *reinterpret_cast<const bf16x8*>(&Q[baseB + (size_t)qrow * NDK + kc * 32 + kg * 8]);
#pragma unroll
        for (int j = 0; j < 8; j++) raw[j] = to_bf16((float)raw[j] * scale);
        qf[kc] = raw;
    }

    f32x4 o[8];
#pragma unroll
    for (int n = 0; n < 8; n++) o[n] = (f32x4){0.f, 0.f, 0.f, 0.f};
    float mrow[4] = {-INFINITY, -INFINITY, -INFINITY, -INFINITY};
    float lrow[4] = {0.f, 0.f, 0.f, 0.f};

    const int nsteps = qb + 1;
    for (int s = 0; s < nsteps; s++) {
        const int kv0 = s * 64;
        // stage K tile [64][128] swizzled: chunk' = chunk ^ (row&7)
#pragma unroll
        for (int i = 0; i < 4; i++) {
            int idx = i * 256 + tid;               // 1024 chunks
            int row = idx >> 4, c = idx & 15;
            bf16x8 v = *reinterpret_cast<const bf16x8*>(&K[baseB + (size_t)(kv0 + row) * NDK + c * 8]);
            *reinterpret_cast<bf16x8*>(&Ks[row][(c ^ (row & 7)) * 8]) = v;
        }
        // stage V^T tile [128][64] swizzled
#pragma unroll
        for (int i = 0; i < 4; i++) {
            int idx = i * 256 + tid;               // 1024 chunks
            int row = idx >> 3, c = idx & 7;
            bf16x8 v = *reinterpret_cast<const bf16x8*>(&Vt[baseVt + (size_t)row * NT + kv0 + c * 8]);
            *reinterpret_cast<bf16x8*>(&Vs[row][(c ^ (row & 7)) * 8]) = v;
        }
        __syncthreads();

        // S = Q K^T  (4 kv-col tiles x 4 k-chunks)
        f32x4 sfr[4];
#pragma unroll
        for (int n = 0; n < 4; n++) sfr[n] = (f32x4){0.f, 0.f, 0.f, 0.f};
#pragma unroll
        for (int n = 0; n < 4; n++) {
            const int krow = n * 16 + r16;
#pragma unroll
            for (int kc = 0; kc < 4; kc++) {
                bf16x8 kf = *reinterpret_cast<const bf16x8*>(&Ks[krow][((kc * 4 + kg) ^ (krow & 7)) * 8]);
                sfr[n] = __builtin_amdgcn_mfma_f32_16x16x32_bf16(qf[kc], kf, sfr[n], 0, 0, 0);
            }
        }

        // causal mask only on the diagonal tile
        if (s == nsteps - 1) {
#pragma unroll
            for (int n = 0; n < 4; n++) {
#pragma unroll
                for (int r = 0; r < 4; r++) {
                    int col = kv0 + n * 16 + r16;
                    int row = q0 + wave * 16 + kg * 4 + r;
                    if (col > row) sfr[n][r] = -INFINITY;
                }
            }
        }

        // row max of this tile
        float pmax[4] = {-INFINITY, -INFINITY, -INFINITY, -INFINITY};
#pragma unroll
        for (int n = 0; n < 4; n++)
#pragma unroll
            for (int r = 0; r < 4; r++) pmax[r] = fmaxf(pmax[r], sfr[n][r]);
#pragma unroll
        for (int d = 1; d < 16; d <<= 1)
#pragma unroll
            for (int r = 0; r < 4; r++)
                pmax[r] = fmaxf(pmax[r], __shfl_xor(pmax[r], d, 64));

        // rescale only if running max grew (exact: THR=0)
        float gmax = -INFINITY;
#pragma unroll
        for (int r = 0; r < 4; r++) gmax = fmaxf(gmax, pmax[r] - mrow[r]);
        if (__any(gmax > 0.f)) {
#pragma unroll
            for (int r = 0; r < 4; r++) {
                float mnew = fmaxf(mrow[r], pmax[r]);
                float corr = __expf(mrow[r] - mnew);
                mrow[r] = mnew;
                lrow[r] *= corr;
#pragma unroll
                for (int n = 0; n < 8; n++) o[n][r] *= corr;
            }
        }

        // P = exp(s - m), row sums, stash to LDS for relayout
        float psum[4] = {0.f, 0.f, 0.f, 0.f};
#pragma unroll
        for (int n = 0; n < 4; n++) {
#pragma unroll
            for (int r = 0; r < 4; r++) {
                float pv = __expf(sfr[n][r] - mrow[r]);
                psum[r] += pv;
                Ps[wave][kg * 4 + r][n * 16 + r16] = to_bf16(pv);
            }
        }
#pragma unroll
        for (int d = 1; d < 16; d <<= 1)
#pragma unroll
            for (int r = 0; r < 4; r++)
                psum[r] += __shfl_xor(psum[r], d, 64);
#pragma unroll
        for (int r = 0; r < 4; r++) lrow[r] += psum[r];

        // O += P V   (P as A-operand from Ps, V^T as B-operand from Vs)
#pragma unroll
        for (int kc2 = 0; kc2 < 2; kc2++) {
            bf16x8 pf = *reinterpret_cast<const bf16x8*>(&Ps[wave][r16][kc2 * 32 + kg * 8]);
#pragma unroll
            for (int n = 0; n < 8; n++) {
                const int vrow = n * 16 + r16;
                bf16x8 vf = *reinterpret_cast<const bf16x8*>(&Vs[vrow][((kc2 * 4 + kg) ^ (vrow & 7)) * 8]);
                o[n] = __builtin_amdgcn_mfma_f32_16x16x32_bf16(pf, vf, o[n], 0, 0, 0);
            }
        }
        __syncthreads();
    }

    float inv[4];
#pragma unroll
    for (int r = 0; r < 4; r++) inv[r] = 1.0f / lrow[r];
#pragma unroll
    for (int n = 0; n < 8; n++)
#pragma unroll
        for (int r = 0; r < 4; r++) {
            int row = q0 + wave * 16 + kg * 4 + r;
            int col = n * 16 + r16;
            out[baseB + (size_t)row * NDK + col] = o[n][r] * inv[r];
        }
}

// ---------------------------------------------------------------------------
extern "C" void kernel_launch(void* const* d_in, const int* in_sizes, int n_in,
                              void* d_out, int out_size, void* d_ws, size_t ws_size,
                              hipStream_t stream) {
    const float* x  = (const float*)d_in[0];
    const float* Wq = (const float*)d_in[1];
    const float* Wk = (const float*)d_in[2];
    const float* Wv = (const float*)d_in[3];
    float* out = (float*)d_out;

    char* ws = (char*)d_ws;
    bf16* Wt  = (bf16*)ws;                        // 3*128*1024*2  = 768 KB
    bf16* qkv = (bf16*)(ws + (1ull << 20));       // 3*16*2048*128*2 = 24 MB
    bf16* Vtg = (bf16*)(ws + (26ull << 20));      // 16*128*2048*2 = 8 MB

    // 1) transpose weights to bf16 [3][128][1024]
    transpose_w_kernel<<<(3 * NDM * NDK) / 256, 256, 0, stream>>>(Wq, Wk, Wv, Wt);

    // 2) QKV projection
    dim3 g1((NB * NT) / 128, 3);
    proj_kernel<<<g1, 256, 0, stream>>>(x, Wt, qkv);

    bf16* Qp = qkv;
    bf16* Kp = qkv + (size_t)(NB * NT) * NDK;
    bf16* Vp = qkv + 2 * (size_t)(NB * NT) * NDK;

    // 2.5) one-time V transpose -> [B][128][T]
    dim3 gt(NT / 64, NB);
    transpose_v_kernel<<<gt, 256, 0, stream>>>(Vp, Vtg);

    // 3) causal flash attention
    dim3 g2(NT / 64, NB);
    attn_kernel<<<g2, 256, 0, stream>>>(Qp, Kp, Vtg, out);
}

// Round 3
// 120.974 us; speedup vs baseline: 2.4697x; 1.6086x over previous
//
#include <hip/hip_runtime.h>
#include <hip/hip_bf16.h>

#define NB 16
#define NT 2048
#define NDM 1024
#define NDK 128

typedef __bf16 bf16;
typedef bf16 bf16x4 __attribute__((ext_vector_type(4)));
typedef bf16 bf16x8 __attribute__((ext_vector_type(8)));
typedef float f32x4 __attribute__((ext_vector_type(4)));

__device__ inline bf16 to_bf16(float f) {
    __hip_bfloat16 h = __float2bfloat16(f);
    return *reinterpret_cast<bf16*>(&h);
}

// ---------------------------------------------------------------------------
// Kernel 1: W [1024][128] f32  ->  Wt bf16 [3][128][1024]  (transposed, K-major)
// ---------------------------------------------------------------------------
__global__ __launch_bounds__(256) void transpose_w_kernel(
        const float* __restrict__ Wq, const float* __restrict__ Wk,
        const float* __restrict__ Wv, bf16* __restrict__ Wt) {
    int idx = blockIdx.x * 256 + threadIdx.x;      // over 3*1024*128
    int w = idx >> 17;                             // / (1024*128)
    int r = idx & (NDM * NDK - 1);
    int k = r >> 7;                                // / 128
    int n = r & (NDK - 1);
    const float* W = (w == 0) ? Wq : ((w == 1) ? Wk : Wv);
    Wt[(size_t)w * NDK * NDM + (size_t)n * NDM + k] = to_bf16(W[(size_t)k * NDK + n]);
}

// ---------------------------------------------------------------------------
// Kernel 2: QKV projection. x[f32, M=B*T x 1024] @ Wt^T -> qkv bf16 [3][M][128]
// Tile: BM=128, BN=128, BK=32. 4 waves in 2x2, each 64x64 (4x4 MFMA frags).
// ---------------------------------------------------------------------------
__global__ __launch_bounds__(256) void proj_kernel(
        const float* __restrict__ x, const bf16* __restrict__ Wt,
        bf16* __restrict__ qkv) {
    __shared__ bf16 As[128][40];
    __shared__ bf16 Bs[128][40];   // [n][k]
    const int tid = threadIdx.x;
    const int lane = tid & 63;
    const int wave = tid >> 6;
    const int wr = wave >> 1, wc = wave & 1;
    const int r16 = lane & 15, kg = lane >> 4;
    const int mb = blockIdx.x;
    const int w = blockIdx.y;
    const float* xA = x + (size_t)mb * 128 * NDM;
    const bf16* Bt = Wt + (size_t)w * NDK * NDM;

    f32x4 acc[4][4];
#pragma unroll
    for (int m = 0; m < 4; m++)
#pragma unroll
        for (int n = 0; n < 4; n++) acc[m][n] = (f32x4){0.f, 0.f, 0.f, 0.f};

    for (int k0 = 0; k0 < NDM; k0 += 32) {
        // stage A: 128x32 f32 -> bf16
#pragma unroll
        for (int p = 0; p < 4; p++) {
            int row = p * 32 + (tid >> 3);
            int c4 = (tid & 7) * 4;
            const float4 v = *reinterpret_cast<const float4*>(&xA[(size_t)row * NDM + k0 + c4]);
            bf16x4 bv = { to_bf16(v.x), to_bf16(v.y), to_bf16(v.z), to_bf16(v.w) };
            *reinterpret_cast<bf16x4*>(&As[row][c4]) = bv;
        }
        // stage B: 128x32 bf16 (already K-contiguous)
#pragma unroll
        for (int p = 0; p < 2; p++) {
            int idx = (p * 256 + tid) * 8;
            int n = idx >> 5;
            int kk = idx & 31;
            *reinterpret_cast<bf16x8*>(&Bs[n][kk]) =
                *reinterpret_cast<const bf16x8*>(&Bt[(size_t)n * NDM + k0 + kk]);
        }
        __syncthreads();
        bf16x8 af[4], bfr[4];
#pragma unroll
        for (int m = 0; m < 4; m++)
            af[m] = *reinterpret_cast<const bf16x8*>(&As[wr * 64 + m * 16 + r16][kg * 8]);
#pragma unroll
        for (int n = 0; n < 4; n++)
            bfr[n] = *reinterpret_cast<const bf16x8*>(&Bs[wc * 64 + n * 16 + r16][kg * 8]);
#pragma unroll
        for (int m = 0; m < 4; m++)
#pragma unroll
            for (int n = 0; n < 4; n++)
                acc[m][n] = __builtin_amdgcn_mfma_f32_16x16x32_bf16(af[m], bfr[n], acc[m][n], 0, 0, 0);
        __syncthreads();
    }

    bf16* outw = qkv + (size_t)w * (size_t)(NB * NT) * NDK;
#pragma unroll
    for (int m = 0; m < 4; m++) {
        int rowb = mb * 128 + wr * 64 + m * 16 + kg * 4;
#pragma unroll
        for (int n = 0; n < 4; n++) {
            int col = wc * 64 + n * 16 + r16;
#pragma unroll
            for (int r = 0; r < 4; r++)
                outw[(size_t)(rowb + r) * NDK + col] = to_bf16(acc[m][n][r]);
        }
    }
}

// ---------------------------------------------------------------------------
// Kernel 2.5: V [B][T][128] bf16 -> Vt [B][128][T] bf16 (one-time transpose)
// ---------------------------------------------------------------------------
__global__ __launch_bounds__(256) void transpose_v_kernel(
        const bf16* __restrict__ V, bf16* __restrict__ Vt) {
    __shared__ bf16 Tl[64][136];   // [t][d], padded
    const int tid = threadIdx.x;
    const int tb = blockIdx.x, b = blockIdx.y;
    const int t0 = tb * 64;
    const size_t ibase = (size_t)b * NT * NDK;
    const size_t obase = (size_t)b * NDK * NT;
#pragma unroll
    for (int p = 0; p < 4; p++) {
        int idx = p * 256 + tid;           // chunk over 64 rows x 16 chunks
        int row = idx >> 4, c = idx & 15;
        *reinterpret_cast<bf16x8*>(&Tl[row][c * 8]) =
            *reinterpret_cast<const bf16x8*>(&V[ibase + (size_t)(t0 + row) * NDK + c * 8]);
    }
    __syncthreads();
#pragma unroll
    for (int p = 0; p < 4; p++) {
        int idx = p * 256 + tid;           // chunk over 128 d-rows x 8 chunks
        int d = idx >> 3, c = idx & 7;
        bf16x8 v;
#pragma unroll
        for (int j = 0; j < 8; j++) v[j] = Tl[c * 8 + j][d];
        *reinterpret_cast<bf16x8*>(&Vt[obase + (size_t)d * NT + t0 + c * 8]) = v;
    }
}

// ---------------------------------------------------------------------------
// Kernel 3: causal flash attention. Q,K bf16 [B][T][128], Vt bf16 [B][128][T].
// 1-D grid of 512; XCD-aware mapping: each XCD owns 2 batches (KV L2-resident).
// Async-STAGE split (T14): next tile's K/V loaded into regs during compute.
// ---------------------------------------------------------------------------
__global__ __launch_bounds__(256) void attn_kernel(
        const bf16* __restrict__ Q, const bf16* __restrict__ K,
        const bf16* __restrict__ Vt, float* __restrict__ out) {
    __shared__ bf16 Ks[64][128];   // [kv][k], swizzled
    __shared__ bf16 Vs[128][64];   // [d][kv], swizzled
    __shared__ bf16 Ps[4][16][72]; // per-wave P relayout buffer (padded)
    const int tid = threadIdx.x, lane = tid & 63, wave = tid >> 6;
    const int r16 = lane & 15, kg = lane >> 4;

    // XCD-aware mapping: blocks round-robin XCDs by bid&7; give each XCD
    // 2 whole batches so its KV working set is 2 MB (< 4 MB L2).
    const int bid = blockIdx.x;
    const int xcd = bid & 7;
    const int j = bid >> 3;                 // 0..63 within XCD
    const int b = xcd * 2 + (j & 1);
    const int qb = (NT / 64 - 1) - (j >> 1);   // longest first
    const int q0 = qb * 64;
    const size_t baseB = (size_t)b * NT * NDK;
    const size_t baseVt = (size_t)b * NDK * NT;

    // Q fragments (A-operand), scale folded in; 16 rows per wave, DK=128
    const float scale = 0.08838834764831843f;  // 1/sqrt(128)
    bf16x8 qf[4];
    const int qrow = q0 + wave * 16 + r16;
#pragma unroll
    for (int kc = 0; kc < 4; kc++) {
        bf16x8 raw = *reinterpret_cast<const bf16x8*>(&Q[baseB + (size_t)qrow * NDK + kc * 32 + kg * 8]);
#pragma unroll
        for (int jj = 0; jj < 8; jj++) raw[jj] = to_bf16((float)raw[jj] * scale);
        qf[kc] = raw;
    }

    f32x4 o[8];
#pragma unroll
    for (int n = 0; n < 8; n++) o[n] = (f32x4){0.f, 0.f, 0.f, 0.f};
    float mrow[4] = {-INFINITY, -INFINITY, -INFINITY, -INFINITY};
    float lrow[4] = {0.f, 0.f, 0.f, 0.f};

    // staging index precompute
    int krow[4], kcol[4], vrow[4], vcol[4];
#pragma unroll
    for (int i = 0; i < 4; i++) {
        int idx = i * 256 + tid;
        krow[i] = idx >> 4; kcol[i] = idx & 15;   // 64 rows x 16 chunks
        vrow[i] = idx >> 3; vcol[i] = idx & 7;    // 128 rows x 8 chunks
    }

    const int nsteps = qb + 1;

    // prologue: prefetch step 0 into regs
    bf16x8 kreg[4], vreg[4];
#pragma unroll
    for (int i = 0; i < 4; i++) {
        kreg[i] = *reinterpret_cast<const bf16x8*>(&K[baseB + (size_t)krow[i] * NDK + kcol[i] * 8]);
        vreg[i] = *reinterpret_cast<const bf16x8*>(&Vt[baseVt + (size_t)vrow[i] * NT + vcol[i] * 8]);
    }

    for (int s = 0; s < nsteps; s++) {
        __syncthreads();   // all waves done reading LDS from previous step
#pragma unroll
        for (int i = 0; i < 4; i++)
            *reinterpret_cast<bf16x8*>(&Ks[krow[i]][(kcol[i] ^ (krow[i] & 7)) * 8]) = kreg[i];
#pragma unroll
        for (int i = 0; i < 4; i++)
            *reinterpret_cast<bf16x8*>(&Vs[vrow[i]][(vcol[i] ^ (vrow[i] & 7)) * 8]) = vreg[i];
        __syncthreads();

        // prefetch next step while computing this one (HBM latency hidden)
        if (s + 1 < nsteps) {
            const int kv0n = (s + 1) * 64;
#pragma unroll
            for (int i = 0; i < 4; i++) {
                kreg[i] = *reinterpret_cast<const bf16x8*>(&K[baseB + (size_t)(kv0n + krow[i]) * NDK + kcol[i] * 8]);
                vreg[i] = *reinterpret_cast<const bf16x8*>(&Vt[baseVt + (size_t)vrow[i] * NT + kv0n + vcol[i] * 8]);
            }
        }

        const int kv0 = s * 64;
        // S = Q K^T  (4 kv-col tiles x 4 k-chunks)
        f32x4 sfr[4];
#pragma unroll
        for (int n = 0; n < 4; n++) sfr[n] = (f32x4){0.f, 0.f, 0.f, 0.f};
#pragma unroll
        for (int n = 0; n < 4; n++) {
            const int krw = n * 16 + r16;
#pragma unroll
            for (int kc = 0; kc < 4; kc++) {
                bf16x8 kf = *reinterpret_cast<const bf16x8*>(&Ks[krw][((kc * 4 + kg) ^ (krw & 7)) * 8]);
                sfr[n] = __builtin_amdgcn_mfma_f32_16x16x32_bf16(qf[kc], kf, sfr[n], 0, 0, 0);
            }
        }

        // causal mask only on the diagonal tile
        if (s == nsteps - 1) {
#pragma unroll
            for (int n = 0; n < 4; n++) {
#pragma unroll
                for (int r = 0; r < 4; r++) {
                    int col = kv0 + n * 16 + r16;
                    int row = q0 + wave * 16 + kg * 4 + r;
                    if (col > row) sfr[n][r] = -INFINITY;
                }
            }
        }

        // row max of this tile
        float pmax[4] = {-INFINITY, -INFINITY, -INFINITY, -INFINITY};
#pragma unroll
        for (int n = 0; n < 4; n++)
#pragma unroll
            for (int r = 0; r < 4; r++) pmax[r] = fmaxf(pmax[r], sfr[n][r]);
#pragma unroll
        for (int d = 1; d < 16; d <<= 1)
#pragma unroll
            for (int r = 0; r < 4; r++)
                pmax[r] = fmaxf(pmax[r], __shfl_xor(pmax[r], d, 64));

        // rescale only if running max grew (exact: THR=0)
        float gmax = -INFINITY;
#pragma unroll
        for (int r = 0; r < 4; r++) gmax = fmaxf(gmax, pmax[r] - mrow[r]);
        if (__any(gmax > 0.f)) {
#pragma unroll
            for (int r = 0; r < 4; r++) {
                float mnew = fmaxf(mrow[r], pmax[r]);
                float corr = __expf(mrow[r] - mnew);
                mrow[r] = mnew;
                lrow[r] *= corr;
#pragma unroll
                for (int n = 0; n < 8; n++) o[n][r] *= corr;
            }
        }

        // P = exp(s - m), row sums, stash to LDS for relayout
        float psum[4] = {0.f, 0.f, 0.f, 0.f};
#pragma unroll
        for (int n = 0; n < 4; n++) {
#pragma unroll
            for (int r = 0; r < 4; r++) {
                float pv = __expf(sfr[n][r] - mrow[r]);
                psum[r] += pv;
                Ps[wave][kg * 4 + r][n * 16 + r16] = to_bf16(pv);
            }
        }
#pragma unroll
        for (int d = 1; d < 16; d <<= 1)
#pragma unroll
            for (int r = 0; r < 4; r++)
                psum[r] += __shfl_xor(psum[r], d, 64);
#pragma unroll
        for (int r = 0; r < 4; r++) lrow[r] += psum[r];

        // O += P V   (P as A-operand from Ps, V^T as B-operand from Vs)
#pragma unroll
        for (int kc2 = 0; kc2 < 2; kc2++) {
            bf16x8 pf = *reinterpret_cast<const bf16x8*>(&Ps[wave][r16][kc2 * 32 + kg * 8]);
#pragma unroll
            for (int n = 0; n < 8; n++) {
                const int vrw = n * 16 + r16;
                bf16x8 vf = *reinterpret_cast<const bf16x8*>(&Vs[vrw][((kc2 * 4 + kg) ^ (vrw & 7)) * 8]);
                o[n] = __builtin_amdgcn_mfma_f32_16x16x32_bf16(pf, vf, o[n], 0, 0, 0);
            }
        }
    }

    float inv[4];
#pragma unroll
    for (int r = 0; r < 4; r++) inv[r] = 1.0f / lrow[r];
#pragma unroll
    for (int n = 0; n < 8; n++)
#pragma unroll
        for (int r = 0; r < 4; r++) {
            int row = q0 + wave * 16 + kg * 4 + r;
            int col = n * 16 + r16;
            out[baseB + (size_t)row * NDK + col] = o[n][r] * inv[r];
        }
}

// ---------------------------------------------------------------------------
extern "C" void kernel_launch(void* const* d_in, const int* in_sizes, int n_in,
                              void* d_out, int out_size, void* d_ws, size_t ws_size,
                              hipStream_t stream) {
    const float* x  = (const float*)d_in[0];
    const float* Wq = (const float*)d_in[1];
    const float* Wk = (const float*)d_in[2];
    const float* Wv = (const float*)d_in[3];
    float* out = (float*)d_out;

    char* ws = (char*)d_ws;
    bf16* Wt  = (bf16*)ws;                        // 3*128*1024*2  = 768 KB
    bf16* qkv = (bf16*)(ws + (1ull << 20));       // 3*16*2048*128*2 = 24 MB
    bf16* Vtg = (bf16*)(ws + (26ull << 20));      // 16*128*2048*2 = 8 MB

    // 1) transpose weights to bf16 [3][128][1024]
    transpose_w_kernel<<<(3 * NDM * NDK) / 256, 256, 0, stream>>>(Wq, Wk, Wv, Wt);

    // 2) QKV projection
    dim3 g1((NB * NT) / 128, 3);
    proj_kernel<<<g1, 256, 0, stream>>>(x, Wt, qkv);

    bf16* Qp = qkv;
    bf16* Kp = qkv + (size_t)(NB * NT) * NDK;
    bf16* Vp = qkv + 2 * (size_t)(NB * NT) * NDK;

    // 2.5) one-time V transpose -> [B][128][T]
    dim3 gt(NT / 64, NB);
    transpose_v_kernel<<<gt, 256, 0, stream>>>(Vp, Vtg);

    // 3) causal flash attention (1-D grid, XCD-aware mapping inside)
    attn_kernel<<<dim3((NT / 64) * NB), 256, 0, stream>>>(Qp, Kp, Vtg, out);
}

// Round 4
// 102.932 us; speedup vs baseline: 2.9025x; 1.1753x over previous
//
#include <hip/hip_runtime.h>
#include <hip/hip_bf16.h>

#define NB 16
#define NT 2048
#define NDM 1024
#define NDK 128

typedef __bf16 bf16;
typedef bf16 bf16x4 __attribute__((ext_vector_type(4)));
typedef bf16 bf16x8 __attribute__((ext_vector_type(8)));
typedef float f32x4 __attribute__((ext_vector_type(4)));

__device__ inline bf16 to_bf16(float f) {
    __hip_bfloat16 h = __float2bfloat16(f);
    return *reinterpret_cast<bf16*>(&h);
}

// ---------------------------------------------------------------------------
// Kernel 1: W [1024][128] f32  ->  Wt bf16 [3][128][1024]  (transposed, K-major)
// ---------------------------------------------------------------------------
__global__ __launch_bounds__(256) void transpose_w_kernel(
        const float* __restrict__ Wq, const float* __restrict__ Wk,
        const float* __restrict__ Wv, bf16* __restrict__ Wt) {
    int idx = blockIdx.x * 256 + threadIdx.x;      // over 3*1024*128
    int w = idx >> 17;                             // / (1024*128)
    int r = idx & (NDM * NDK - 1);
    int k = r >> 7;                                // / 128
    int n = r & (NDK - 1);
    const float* W = (w == 0) ? Wq : ((w == 1) ? Wk : Wv);
    Wt[(size_t)w * NDK * NDM + (size_t)n * NDM + k] = to_bf16(W[(size_t)k * NDK + n]);
}

// ---------------------------------------------------------------------------
// Kernel 2: QKV projection. x[f32, M=B*T x 1024] @ Wt^T -> q,k bf16 [M][128];
// for w==2 the epilogue writes V transposed directly: Vt [B][128][T].
// ---------------------------------------------------------------------------
__global__ __launch_bounds__(256) void proj_kernel(
        const float* __restrict__ x, const bf16* __restrict__ Wt,
        bf16* __restrict__ qkv, bf16* __restrict__ Vt) {
    __shared__ bf16 As[128][40];
    __shared__ bf16 Bs[128][40];   // [n][k]
    const int tid = threadIdx.x;
    const int lane = tid & 63;
    const int wave = tid >> 6;
    const int wr = wave >> 1, wc = wave & 1;
    const int r16 = lane & 15, kg = lane >> 4;
    const int mb = blockIdx.x;
    const int w = blockIdx.y;
    const float* xA = x + (size_t)mb * 128 * NDM;
    const bf16* Bt = Wt + (size_t)w * NDK * NDM;

    f32x4 acc[4][4];
#pragma unroll
    for (int m = 0; m < 4; m++)
#pragma unroll
        for (int n = 0; n < 4; n++) acc[m][n] = (f32x4){0.f, 0.f, 0.f, 0.f};

    for (int k0 = 0; k0 < NDM; k0 += 32) {
        // stage A: 128x32 f32 -> bf16
#pragma unroll
        for (int p = 0; p < 4; p++) {
            int row = p * 32 + (tid >> 3);
            int c4 = (tid & 7) * 4;
            const float4 v = *reinterpret_cast<const float4*>(&xA[(size_t)row * NDM + k0 + c4]);
            bf16x4 bv = { to_bf16(v.x), to_bf16(v.y), to_bf16(v.z), to_bf16(v.w) };
            *reinterpret_cast<bf16x4*>(&As[row][c4]) = bv;
        }
        // stage B: 128x32 bf16 (already K-contiguous)
#pragma unroll
        for (int p = 0; p < 2; p++) {
            int idx = (p * 256 + tid) * 8;
            int n = idx >> 5;
            int kk = idx & 31;
            *reinterpret_cast<bf16x8*>(&Bs[n][kk]) =
                *reinterpret_cast<const bf16x8*>(&Bt[(size_t)n * NDM + k0 + kk]);
        }
        __syncthreads();
        bf16x8 af[4], bfr[4];
#pragma unroll
        for (int m = 0; m < 4; m++)
            af[m] = *reinterpret_cast<const bf16x8*>(&As[wr * 64 + m * 16 + r16][kg * 8]);
#pragma unroll
        for (int n = 0; n < 4; n++)
            bfr[n] = *reinterpret_cast<const bf16x8*>(&Bs[wc * 64 + n * 16 + r16][kg * 8]);
#pragma unroll
        for (int m = 0; m < 4; m++)
#pragma unroll
            for (int n = 0; n < 4; n++)
                acc[m][n] = __builtin_amdgcn_mfma_f32_16x16x32_bf16(af[m], bfr[n], acc[m][n], 0, 0, 0);
        __syncthreads();
    }

    if (w < 2) {
        bf16* outw = qkv + (size_t)w * (size_t)(NB * NT) * NDK;
#pragma unroll
        for (int m = 0; m < 4; m++) {
            int rowb = mb * 128 + wr * 64 + m * 16 + kg * 4;
#pragma unroll
            for (int n = 0; n < 4; n++) {
                int col = wc * 64 + n * 16 + r16;
#pragma unroll
                for (int r = 0; r < 4; r++)
                    outw[(size_t)(rowb + r) * NDK + col] = to_bf16(acc[m][n][r]);
            }
        }
    } else {
        // V: write transposed [B][128][T] (4 consecutive t per 8B store)
        const int b = mb >> 4;
        const int tl0 = (mb & 15) * 128 + wr * 64;
        bf16* Vb = Vt + (size_t)b * NDK * NT;
#pragma unroll
        for (int m = 0; m < 4; m++) {
            int tl = tl0 + m * 16 + kg * 4;
#pragma unroll
            for (int n = 0; n < 4; n++) {
                int d = wc * 64 + n * 16 + r16;
                bf16x4 pv = { to_bf16(acc[m][n][0]), to_bf16(acc[m][n][1]),
                              to_bf16(acc[m][n][2]), to_bf16(acc[m][n][3]) };
                *reinterpret_cast<bf16x4*>(&Vb[(size_t)d * NT + tl]) = pv;
            }
        }
    }
}

// ---------------------------------------------------------------------------
// Kernel 3: causal flash attention, swapped-QK^T softmax (S^T = K·Q^T so each
// lane owns one q-row's kv-slice -> in-lane reductions). K/V LDS double-
// buffered, one barrier per step, reg-prefetch 1 tile ahead (T14).
// ---------------------------------------------------------------------------
__global__ __launch_bounds__(256) void attn_kernel(
        const bf16* __restrict__ Q, const bf16* __restrict__ K,
        const bf16* __restrict__ Vt, float* __restrict__ out) {
    __shared__ bf16 Ks[2][64][128];   // [buf][kv][k], swizzled
    __shared__ bf16 Vs[2][128][64];   // [buf][d][kv], swizzled
    __shared__ bf16 Ps[4][16][72];    // [wave][q-local][kv], padded
    const int tid = threadIdx.x, lane = tid & 63, wave = tid >> 6;
    const int r16 = lane & 15, kg = lane >> 4;

    // XCD-aware mapping: each XCD owns 2 batches (KV working set 2MB < L2)
    const int bid = blockIdx.x;
    const int xcd = bid & 7;
    const int j = bid >> 3;
    const int b = xcd * 2 + (j & 1);
    const int qb = (NT / 64 - 1) - (j >> 1);   // longest first
    const int q0 = qb * 64;
    const size_t baseB = (size_t)b * NT * NDK;
    const size_t baseVt = (size_t)b * NDK * NT;

    const float scale = 0.08838834764831843f;  // 1/sqrt(128)
    bf16x8 qf[4];
    const int qglob = q0 + wave * 16 + r16;    // this lane's q-row
#pragma unroll
    for (int kc = 0; kc < 4; kc++) {
        bf16x8 raw = *reinterpret_cast<const bf16x8*>(&Q[baseB + (size_t)qglob * NDK + kc * 32 + kg * 8]);
#pragma unroll
        for (int jj = 0; jj < 8; jj++) raw[jj] = to_bf16((float)raw[jj] * scale);
        qf[kc] = raw;
    }

    f32x4 o[8];
#pragma unroll
    for (int n = 0; n < 8; n++) o[n] = (f32x4){0.f, 0.f, 0.f, 0.f};
    float mrun = -INFINITY;   // running max for q = qglob
    float lrun = 0.f;         // running denom

    int krow[4], kcol[4], vrow[4], vcol[4];
#pragma unroll
    for (int i = 0; i < 4; i++) {
        int idx = i * 256 + tid;
        krow[i] = idx >> 4; kcol[i] = idx & 15;   // 64 rows x 16 chunks
        vrow[i] = idx >> 3; vcol[i] = idx & 7;    // 128 rows x 8 chunks
    }

    const int nsteps = qb + 1;
    bf16x8 kreg[4], vreg[4];
    // prologue: tile 0 -> regs -> buf0; issue tile 1 loads
#pragma unroll
    for (int i = 0; i < 4; i++) {
        kreg[i] = *reinterpret_cast<const bf16x8*>(&K[baseB + (size_t)krow[i] * NDK + kcol[i] * 8]);
        vreg[i] = *reinterpret_cast<const bf16x8*>(&Vt[baseVt + (size_t)vrow[i] * NT + vcol[i] * 8]);
    }
#pragma unroll
    for (int i = 0; i < 4; i++) {
        *reinterpret_cast<bf16x8*>(&Ks[0][krow[i]][(kcol[i] ^ (krow[i] & 7)) * 8]) = kreg[i];
        *reinterpret_cast<bf16x8*>(&Vs[0][vrow[i]][(vcol[i] ^ (vrow[i] & 7)) * 8]) = vreg[i];
    }
    if (nsteps > 1) {
#pragma unroll
        for (int i = 0; i < 4; i++) {
            kreg[i] = *reinterpret_cast<const bf16x8*>(&K[baseB + (size_t)(64 + krow[i]) * NDK + kcol[i] * 8]);
            vreg[i] = *reinterpret_cast<const bf16x8*>(&Vt[baseVt + (size_t)vrow[i] * NT + 64 + vcol[i] * 8]);
        }
    }
    __syncthreads();

    for (int s = 0; s < nsteps; s++) {
        const int cur = s & 1;
        const int kv0 = s * 64;

        // S^T = K Q^T : D[kv][q], q = r16 (lane-local row), kv = n*16+kg*4+r
        f32x4 sfr[4];
#pragma unroll
        for (int n = 0; n < 4; n++) sfr[n] = (f32x4){0.f, 0.f, 0.f, 0.f};
#pragma unroll
        for (int n = 0; n < 4; n++) {
            const int krw = n * 16 + r16;
#pragma unroll
            for (int kc = 0; kc < 4; kc++) {
                bf16x8 kf = *reinterpret_cast<const bf16x8*>(&Ks[cur][krw][((kc * 4 + kg) ^ (krw & 7)) * 8]);
                sfr[n] = __builtin_amdgcn_mfma_f32_16x16x32_bf16(kf, qf[kc], sfr[n], 0, 0, 0);
            }
        }

        // causal mask only on diagonal tile: kv > q
        if (s == nsteps - 1) {
#pragma unroll
            for (int n = 0; n < 4; n++)
#pragma unroll
                for (int r = 0; r < 4; r++)
                    if (kv0 + n * 16 + kg * 4 + r > qglob) sfr[n][r] = -INFINITY;
        }

        // tile max: 15 in-lane + 2 cross-kg shuffles
        float pm = -INFINITY;
#pragma unroll
        for (int n = 0; n < 4; n++) {
            float t0 = fmaxf(fmaxf(sfr[n][0], sfr[n][1]), fmaxf(sfr[n][2], sfr[n][3]));
            pm = fmaxf(pm, t0);
        }
        pm = fmaxf(pm, __shfl_xor(pm, 16, 64));
        pm = fmaxf(pm, __shfl_xor(pm, 32, 64));

        // rescale O only if running max grew
        if (__any(pm > mrun)) {
            float mnew = fmaxf(mrun, pm);
            float corr = __expf(mrun - mnew);
            mrun = mnew;
            lrun *= corr;
            float co[4];
#pragma unroll
            for (int r = 0; r < 4; r++) co[r] = __shfl(corr, kg * 4 + r, 64);
#pragma unroll
            for (int n = 0; n < 8; n++)
#pragma unroll
                for (int r = 0; r < 4; r++) o[n][r] *= co[r];
        }

        // P = exp(S - m): in-lane sum, pack 4 bf16 per ds_write_b64
        float ps = 0.f;
#pragma unroll
        for (int n = 0; n < 4; n++) {
            bf16x4 pw;
#pragma unroll
            for (int r = 0; r < 4; r++) {
                float pv = __expf(sfr[n][r] - mrun);
                ps += pv;
                pw[r] = to_bf16(pv);
            }
            *reinterpret_cast<bf16x4*>(&Ps[wave][r16][n * 16 + kg * 4]) = pw;
        }
        ps += __shfl_xor(ps, 16, 64);
        ps += __shfl_xor(ps, 32, 64);
        lrun += ps;

        // O += P V
#pragma unroll
        for (int kc2 = 0; kc2 < 2; kc2++) {
            bf16x8 pf = *reinterpret_cast<const bf16x8*>(&Ps[wave][r16][kc2 * 32 + kg * 8]);
#pragma unroll
            for (int n = 0; n < 8; n++) {
                const int vrw = n * 16 + r16;
                bf16x8 vf = *reinterpret_cast<const bf16x8*>(&Vs[cur][vrw][((kc2 * 4 + kg) ^ (vrw & 7)) * 8]);
                o[n] = __builtin_amdgcn_mfma_f32_16x16x32_bf16(pf, vf, o[n], 0, 0, 0);
            }
        }

        // stage tile s+1 into the other buffer; issue loads for s+2
        if (s + 1 < nsteps) {
#pragma unroll
            for (int i = 0; i < 4; i++) {
                *reinterpret_cast<bf16x8*>(&Ks[1 - cur][krow[i]][(kcol[i] ^ (krow[i] & 7)) * 8]) = kreg[i];
                *reinterpret_cast<bf16x8*>(&Vs[1 - cur][vrow[i]][(vcol[i] ^ (vrow[i] & 7)) * 8]) = vreg[i];
            }
            if (s + 2 < nsteps) {
                const int kv2 = (s + 2) * 64;
#pragma unroll
                for (int i = 0; i < 4; i++) {
                    kreg[i] = *reinterpret_cast<const bf16x8*>(&K[baseB + (size_t)(kv2 + krow[i]) * NDK + kcol[i] * 8]);
                    vreg[i] = *reinterpret_cast<const bf16x8*>(&Vt[baseVt + (size_t)vrow[i] * NT + kv2 + vcol[i] * 8]);
                }
            }
        }
        __syncthreads();
    }

    float linv = 1.0f / lrun;
    float li[4];
#pragma unroll
    for (int r = 0; r < 4; r++) li[r] = __shfl(linv, kg * 4 + r, 64);
#pragma unroll
    for (int n = 0; n < 8; n++)
#pragma unroll
        for (int r = 0; r < 4; r++) {
            int row = q0 + wave * 16 + kg * 4 + r;
            int col = n * 16 + r16;
            out[baseB + (size_t)row * NDK + col] = o[n][r] * li[r];
        }
}

// ---------------------------------------------------------------------------
extern "C" void kernel_launch(void* const* d_in, const int* in_sizes, int n_in,
                              void* d_out, int out_size, void* d_ws, size_t ws_size,
                              hipStream_t stream) {
    const float* x  = (const float*)d_in[0];
    const float* Wq = (const float*)d_in[1];
    const float* Wk = (const float*)d_in[2];
    const float* Wv = (const float*)d_in[3];
    float* out = (float*)d_out;

    char* ws = (char*)d_ws;
    bf16* Wt  = (bf16*)ws;                        // 3*128*1024*2  = 768 KB
    bf16* qkv = (bf16*)(ws + (1ull << 20));       // Q,K planes: 16 MB
    bf16* Vtg = (bf16*)(ws + (26ull << 20));      // V^T [B][128][T]: 8 MB

    // 1) transpose weights to bf16 [3][128][1024]
    transpose_w_kernel<<<(3 * NDM * NDK) / 256, 256, 0, stream>>>(Wq, Wk, Wv, Wt);

    // 2) QKV projection (V written pre-transposed)
    dim3 g1((NB * NT) / 128, 3);
    proj_kernel<<<g1, 256, 0, stream>>>(x, Wt, qkv, Vtg);

    bf16* Qp = qkv;
    bf16* Kp = qkv + (size_t)(NB * NT) * NDK;

    // 3) causal flash attention (1-D grid, XCD-aware mapping inside)
    attn_kernel<<<dim3((NT / 64) * NB), 256, 0, stream>>>(Qp, Kp, Vtg, out);
}

// Round 5
// 101.861 us; speedup vs baseline: 2.9331x; 1.0105x over previous
//
#include <hip/hip_runtime.h>
#include <hip/hip_bf16.h>

#define NB 16
#define NT 2048
#define NDM 1024
#define NDK 128

typedef __bf16 bf16;
typedef bf16 bf16x4 __attribute__((ext_vector_type(4)));
typedef bf16 bf16x8 __attribute__((ext_vector_type(8)));
typedef float f32x4 __attribute__((ext_vector_type(4)));

__device__ inline bf16 to_bf16(float f) {
    __hip_bfloat16 h = __float2bfloat16(f);
    return *reinterpret_cast<bf16*>(&h);
}

// ---------------------------------------------------------------------------
// Kernel 1: W [1024][128] f32  ->  Wt bf16 [3][128][1024]  (transposed, K-major)
// ---------------------------------------------------------------------------
__global__ __launch_bounds__(256) void transpose_w_kernel(
        const float* __restrict__ Wq, const float* __restrict__ Wk,
        const float* __restrict__ Wv, bf16* __restrict__ Wt) {
    int idx = blockIdx.x * 256 + threadIdx.x;      // over 3*1024*128
    int w = idx >> 17;                             // / (1024*128)
    int r = idx & (NDM * NDK - 1);
    int k = r >> 7;                                // / 128
    int n = r & (NDK - 1);
    const float* W = (w == 0) ? Wq : ((w == 1) ? Wk : Wv);
    Wt[(size_t)w * NDK * NDM + (size_t)n * NDM + k] = to_bf16(W[(size_t)k * NDK + n]);
}

// ---------------------------------------------------------------------------
// Kernel 2: QKV projection. x[f32, M=B*T x 1024] @ Wt^T -> q,k bf16 [M][128];
// for w==2 the epilogue restages the tile in LDS and writes V transposed
// ([B][128][T]) with 256B-coalesced bf16x8 stores (R4's scattered 8B stores
// were the 76us regression).
// ---------------------------------------------------------------------------
__global__ __launch_bounds__(256) void proj_kernel(
        const float* __restrict__ x, const bf16* __restrict__ Wt,
        bf16* __restrict__ qkv, bf16* __restrict__ Vt) {
    // union: As/Bs (20.5 KB, K-loop) | Tl (34.8 KB, w==2 epilogue only)
    __shared__ __align__(16) char smem[128 * 136 * 2];
    bf16 (*As)[40] = reinterpret_cast<bf16(*)[40]>(smem);          // 10240 B
    bf16 (*Bs)[40] = reinterpret_cast<bf16(*)[40]>(smem + 10240);  // 10240 B
    bf16 (*Tl)[136] = reinterpret_cast<bf16(*)[136]>(smem);        // 34816 B

    const int tid = threadIdx.x;
    const int lane = tid & 63;
    const int wave = tid >> 6;
    const int wr = wave >> 1, wc = wave & 1;
    const int r16 = lane & 15, kg = lane >> 4;
    const int mb = blockIdx.x;
    const int w = blockIdx.y;
    const float* xA = x + (size_t)mb * 128 * NDM;
    const bf16* Bt = Wt + (size_t)w * NDK * NDM;

    f32x4 acc[4][4];
#pragma unroll
    for (int m = 0; m < 4; m++)
#pragma unroll
        for (int n = 0; n < 4; n++) acc[m][n] = (f32x4){0.f, 0.f, 0.f, 0.f};

    for (int k0 = 0; k0 < NDM; k0 += 32) {
        // stage A: 128x32 f32 -> bf16
#pragma unroll
        for (int p = 0; p < 4; p++) {
            int row = p * 32 + (tid >> 3);
            int c4 = (tid & 7) * 4;
            const float4 v = *reinterpret_cast<const float4*>(&xA[(size_t)row * NDM + k0 + c4]);
            bf16x4 bv = { to_bf16(v.x), to_bf16(v.y), to_bf16(v.z), to_bf16(v.w) };
            *reinterpret_cast<bf16x4*>(&As[row][c4]) = bv;
        }
        // stage B: 128x32 bf16 (already K-contiguous)
#pragma unroll
        for (int p = 0; p < 2; p++) {
            int idx = (p * 256 + tid) * 8;
            int n = idx >> 5;
            int kk = idx & 31;
            *reinterpret_cast<bf16x8*>(&Bs[n][kk]) =
                *reinterpret_cast<const bf16x8*>(&Bt[(size_t)n * NDM + k0 + kk]);
        }
        __syncthreads();
        bf16x8 af[4], bfr[4];
#pragma unroll
        for (int m = 0; m < 4; m++)
            af[m] = *reinterpret_cast<const bf16x8*>(&As[wr * 64 + m * 16 + r16][kg * 8]);
#pragma unroll
        for (int n = 0; n < 4; n++)
            bfr[n] = *reinterpret_cast<const bf16x8*>(&Bs[wc * 64 + n * 16 + r16][kg * 8]);
#pragma unroll
        for (int m = 0; m < 4; m++)
#pragma unroll
            for (int n = 0; n < 4; n++)
                acc[m][n] = __builtin_amdgcn_mfma_f32_16x16x32_bf16(af[m], bfr[n], acc[m][n], 0, 0, 0);
        __syncthreads();
    }

    if (w < 2) {
        bf16* outw = qkv + (size_t)w * (size_t)(NB * NT) * NDK;
#pragma unroll
        for (int m = 0; m < 4; m++) {
            int rowb = mb * 128 + wr * 64 + m * 16 + kg * 4;
#pragma unroll
            for (int n = 0; n < 4; n++) {
                int col = wc * 64 + n * 16 + r16;
#pragma unroll
                for (int r = 0; r < 4; r++)
                    outw[(size_t)(rowb + r) * NDK + col] = to_bf16(acc[m][n][r]);
            }
        }
    } else {
        // V: restage transposed tile in LDS, then coalesced stores.
        // acc[m][n][r] maps to t_local = wr*64+m*16+kg*4+r, d = wc*64+n*16+r16
#pragma unroll
        for (int m = 0; m < 4; m++) {
            int tl = wr * 64 + m * 16 + kg * 4;
#pragma unroll
            for (int n = 0; n < 4; n++) {
                int d = wc * 64 + n * 16 + r16;
                bf16x4 pv = { to_bf16(acc[m][n][0]), to_bf16(acc[m][n][1]),
                              to_bf16(acc[m][n][2]), to_bf16(acc[m][n][3]) };
                *reinterpret_cast<bf16x4*>(&Tl[d][tl]) = pv;
            }
        }
        __syncthreads();
        const int b = mb >> 4;
        const int t0 = (mb & 15) * 128;
        bf16* Vb = Vt + (size_t)b * NDK * NT;
#pragma unroll
        for (int p = 0; p < 8; p++) {
            int idx = p * 256 + tid;         // 2048 chunks: 128 d-rows x 16
            int d = idx >> 4, c = idx & 15;
            *reinterpret_cast<bf16x8*>(&Vb[(size_t)d * NT + t0 + c * 8]) =
                *reinterpret_cast<const bf16x8*>(&Tl[d][c * 8]);
        }
    }
}

// ---------------------------------------------------------------------------
// Kernel 3: causal flash attention, swapped-QK^T softmax (S^T = K·Q^T so each
// lane owns one q-row's kv-slice -> in-lane reductions). K/V LDS double-
// buffered, one barrier per step, reg-prefetch 1 tile ahead (T14).
// ---------------------------------------------------------------------------
__global__ __launch_bounds__(256) void attn_kernel(
        const bf16* __restrict__ Q, const bf16* __restrict__ K,
        const bf16* __restrict__ Vt, float* __restrict__ out) {
    __shared__ bf16 Ks[2][64][128];   // [buf][kv][k], swizzled
    __shared__ bf16 Vs[2][128][64];   // [buf][d][kv], swizzled
    __shared__ bf16 Ps[4][16][72];    // [wave][q-local][kv], padded
    const int tid = threadIdx.x, lane = tid & 63, wave = tid >> 6;
    const int r16 = lane & 15, kg = lane >> 4;

    // XCD-aware mapping: each XCD owns 2 batches (KV working set 2MB < L2)
    const int bid = blockIdx.x;
    const int xcd = bid & 7;
    const int j = bid >> 3;
    const int b = xcd * 2 + (j & 1);
    const int qb = (NT / 64 - 1) - (j >> 1);   // longest first
    const int q0 = qb * 64;
    const size_t baseB = (size_t)b * NT * NDK;
    const size_t baseVt = (size_t)b * NDK * NT;

    const float scale = 0.08838834764831843f;  // 1/sqrt(128)
    bf16x8 qf[4];
    const int qglob = q0 + wave * 16 + r16;    // this lane's q-row
#pragma unroll
    for (int kc = 0; kc < 4; kc++) {
        bf16x8 raw = *reinterpret_cast<const bf16x8*>(&Q[baseB + (size_t)qglob * NDK + kc * 32 + kg * 8]);
#pragma unroll
        for (int jj = 0; jj < 8; jj++) raw[jj] = to_bf16((float)raw[jj] * scale);
        qf[kc] = raw;
    }

    f32x4 o[8];
#pragma unroll
    for (int n = 0; n < 8; n++) o[n] = (f32x4){0.f, 0.f, 0.f, 0.f};
    float mrun = -INFINITY;   // running max for q = qglob
    float lrun = 0.f;         // running denom

    int krow[4], kcol[4], vrow[4], vcol[4];
#pragma unroll
    for (int i = 0; i < 4; i++) {
        int idx = i * 256 + tid;
        krow[i] = idx >> 4; kcol[i] = idx & 15;   // 64 rows x 16 chunks
        vrow[i] = idx >> 3; vcol[i] = idx & 7;    // 128 rows x 8 chunks
    }

    const int nsteps = qb + 1;
    bf16x8 kreg[4], vreg[4];
    // prologue: tile 0 -> regs -> buf0; issue tile 1 loads
#pragma unroll
    for (int i = 0; i < 4; i++) {
        kreg[i] = *reinterpret_cast<const bf16x8*>(&K[baseB + (size_t)krow[i] * NDK + kcol[i] * 8]);
        vreg[i] = *reinterpret_cast<const bf16x8*>(&Vt[baseVt + (size_t)vrow[i] * NT + vcol[i] * 8]);
    }
#pragma unroll
    for (int i = 0; i < 4; i++) {
        *reinterpret_cast<bf16x8*>(&Ks[0][krow[i]][(kcol[i] ^ (krow[i] & 7)) * 8]) = kreg[i];
        *reinterpret_cast<bf16x8*>(&Vs[0][vrow[i]][(vcol[i] ^ (vrow[i] & 7)) * 8]) = vreg[i];
    }
    if (nsteps > 1) {
#pragma unroll
        for (int i = 0; i < 4; i++) {
            kreg[i] = *reinterpret_cast<const bf16x8*>(&K[baseB + (size_t)(64 + krow[i]) * NDK + kcol[i] * 8]);
            vreg[i] = *reinterpret_cast<const bf16x8*>(&Vt[baseVt + (size_t)vrow[i] * NT + 64 + vcol[i] * 8]);
        }
    }
    __syncthreads();

    for (int s = 0; s < nsteps; s++) {
        const int cur = s & 1;
        const int kv0 = s * 64;

        // S^T = K Q^T : D[kv][q], q = r16 (lane-local row), kv = n*16+kg*4+r
        f32x4 sfr[4];
#pragma unroll
        for (int n = 0; n < 4; n++) sfr[n] = (f32x4){0.f, 0.f, 0.f, 0.f};
#pragma unroll
        for (int n = 0; n < 4; n++) {
            const int krw = n * 16 + r16;
#pragma unroll
            for (int kc = 0; kc < 4; kc++) {
                bf16x8 kf = *reinterpret_cast<const bf16x8*>(&Ks[cur][krw][((kc * 4 + kg) ^ (krw & 7)) * 8]);
                sfr[n] = __builtin_amdgcn_mfma_f32_16x16x32_bf16(kf, qf[kc], sfr[n], 0, 0, 0);
            }
        }

        // causal mask only on diagonal tile: kv > q
        if (s == nsteps - 1) {
#pragma unroll
            for (int n = 0; n < 4; n++)
#pragma unroll
                for (int r = 0; r < 4; r++)
                    if (kv0 + n * 16 + kg * 4 + r > qglob) sfr[n][r] = -INFINITY;
        }

        // tile max: 15 in-lane + 2 cross-kg shuffles
        float pm = -INFINITY;
#pragma unroll
        for (int n = 0; n < 4; n++) {
            float t0 = fmaxf(fmaxf(sfr[n][0], sfr[n][1]), fmaxf(sfr[n][2], sfr[n][3]));
            pm = fmaxf(pm, t0);
        }
        pm = fmaxf(pm, __shfl_xor(pm, 16, 64));
        pm = fmaxf(pm, __shfl_xor(pm, 32, 64));

        // rescale O only if running max grew
        if (__any(pm > mrun)) {
            float mnew = fmaxf(mrun, pm);
            float corr = __expf(mrun - mnew);
            mrun = mnew;
            lrun *= corr;
            float co[4];
#pragma unroll
            for (int r = 0; r < 4; r++) co[r] = __shfl(corr, kg * 4 + r, 64);
#pragma unroll
            for (int n = 0; n < 8; n++)
#pragma unroll
                for (int r = 0; r < 4; r++) o[n][r] *= co[r];
        }

        // P = exp(S - m): in-lane sum, pack 4 bf16 per ds_write_b64
        float ps = 0.f;
#pragma unroll
        for (int n = 0; n < 4; n++) {
            bf16x4 pw;
#pragma unroll
            for (int r = 0; r < 4; r++) {
                float pv = __expf(sfr[n][r] - mrun);
                ps += pv;
                pw[r] = to_bf16(pv);
            }
            *reinterpret_cast<bf16x4*>(&Ps[wave][r16][n * 16 + kg * 4]) = pw;
        }
        ps += __shfl_xor(ps, 16, 64);
        ps += __shfl_xor(ps, 32, 64);
        lrun += ps;

        // O += P V
#pragma unroll
        for (int kc2 = 0; kc2 < 2; kc2++) {
            bf16x8 pf = *reinterpret_cast<const bf16x8*>(&Ps[wave][r16][kc2 * 32 + kg * 8]);
#pragma unroll
            for (int n = 0; n < 8; n++) {
                const int vrw = n * 16 + r16;
                bf16x8 vf = *reinterpret_cast<const bf16x8*>(&Vs[cur][vrw][((kc2 * 4 + kg) ^ (vrw & 7)) * 8]);
                o[n] = __builtin_amdgcn_mfma_f32_16x16x32_bf16(pf, vf, o[n], 0, 0, 0);
            }
        }

        // stage tile s+1 into the other buffer; issue loads for s+2
        if (s + 1 < nsteps) {
#pragma unroll
            for (int i = 0; i < 4; i++) {
                *reinterpret_cast<bf16x8*>(&Ks[1 - cur][krow[i]][(kcol[i] ^ (krow[i] & 7)) * 8]) = kreg[i];
                *reinterpret_cast<bf16x8*>(&Vs[1 - cur][vrow[i]][(vcol[i] ^ (vrow[i] & 7)) * 8]) = vreg[i];
            }
            if (s + 2 < nsteps) {
                const int kv2 = (s + 2) * 64;
#pragma unroll
                for (int i = 0; i < 4; i++) {
                    kreg[i] = *reinterpret_cast<const bf16x8*>(&K[baseB + (size_t)(kv2 + krow[i]) * NDK + kcol[i] * 8]);
                    vreg[i] = *reinterpret_cast<const bf16x8*>(&Vt[baseVt + (size_t)vrow[i] * NT + kv2 + vcol[i] * 8]);
                }
            }
        }
        __syncthreads();
    }

    float linv = 1.0f / lrun;
    float li[4];
#pragma unroll
    for (int r = 0; r < 4; r++) li[r] = __shfl(linv, kg * 4 + r, 64);
#pragma unroll
    for (int n = 0; n < 8; n++)
#pragma unroll
        for (int r = 0; r < 4; r++) {
            int row = q0 + wave * 16 + kg * 4 + r;
            int col = n * 16 + r16;
            out[baseB + (size_t)row * NDK + col] = o[n][r] * li[r];
        }
}

// ---------------------------------------------------------------------------
extern "C" void kernel_launch(void* const* d_in, const int* in_sizes, int n_in,
                              void* d_out, int out_size, void* d_ws, size_t ws_size,
                              hipStream_t stream) {
    const float* x  = (const float*)d_in[0];
    const float* Wq = (const float*)d_in[1];
    const float* Wk = (const float*)d_in[2];
    const float* Wv = (const float*)d_in[3];
    float* out = (float*)d_out;

    char* ws = (char*)d_ws;
    bf16* Wt  = (bf16*)ws;                        // 3*128*1024*2  = 768 KB
    bf16* qkv = (bf16*)(ws + (1ull << 20));       // Q,K planes: 16 MB
    bf16* Vtg = (bf16*)(ws + (26ull << 20));      // V^T [B][128][T]: 8 MB

    // 1) transpose weights to bf16 [3][128][1024]
    transpose_w_kernel<<<(3 * NDM * NDK) / 256, 256, 0, stream>>>(Wq, Wk, Wv, Wt);

    // 2) QKV projection (V written pre-transposed via LDS restage)
    dim3 g1((NB * NT) / 128, 3);
    proj_kernel<<<g1, 256, 0, stream>>>(x, Wt, qkv, Vtg);

    bf16* Qp = qkv;
    bf16* Kp = qkv + (size_t)(NB * NT) * NDK;

    // 3) causal flash attention (1-D grid, XCD-aware mapping inside)
    attn_kernel<<<dim3((NT / 64) * NB), 256, 0, stream>>>(Qp, Kp, Vtg, out);
}

// Round 7
// 97.850 us; speedup vs baseline: 3.0533x; 1.0410x over previous
//
#include <hip/hip_runtime.h>
#include <hip/hip_bf16.h>

#define NB 16
#define NT 2048
#define NDM 1024
#define NDK 128

typedef __bf16 bf16;
typedef bf16 bf16x4 __attribute__((ext_vector_type(4)));
typedef bf16 bf16x8 __attribute__((ext_vector_type(8)));
typedef float f32x4 __attribute__((ext_vector_type(4)));

__device__ inline bf16 to_bf16(float f) {
    __hip_bfloat16 h = __float2bfloat16(f);
    return *reinterpret_cast<bf16*>(&h);
}

// async 16B global -> LDS (linear dest: wave base + lane*16)
__device__ inline void gload_lds16(const void* g, void* l) {
    __builtin_amdgcn_global_load_lds(
        (const __attribute__((address_space(1))) unsigned int*)g,
        (__attribute__((address_space(3))) unsigned int*)l, 16, 0, 0);
}

// ---------------------------------------------------------------------------
// Kernel 1: W [1024][128] f32  ->  Wt bf16 [3][128][1024]  (transposed, K-major)
// ---------------------------------------------------------------------------
__global__ __launch_bounds__(256) void transpose_w_kernel(
        const float* __restrict__ Wq, const float* __restrict__ Wk,
        const float* __restrict__ Wv, bf16* __restrict__ Wt) {
    int idx = blockIdx.x * 256 + threadIdx.x;      // over 3*1024*128
    int w = idx >> 17;                             // / (1024*128)
    int r = idx & (NDM * NDK - 1);
    int k = r >> 7;                                // / 128
    int n = r & (NDK - 1);
    const float* W = (w == 0) ? Wq : ((w == 1) ? Wk : Wv);
    Wt[(size_t)w * NDK * NDM + (size_t)n * NDM + k] = to_bf16(W[(size_t)k * NDK + n]);
}

// ---------------------------------------------------------------------------
// Kernel 2: QKV projection, m97-style K-loop:
//  - A tile (x, f32) staged RAW via global_load_lds, converted after ds_read
//  - B tile (Wt, bf16) staged via global_load_lds
//  - double-buffered LDS, 1 barrier/K-step, stage k+1 during compute of k
//  - XOR swizzle via pre-swizzled global source (A: c^=(row&7); B: c^=((row>>1)&3))
// ---------------------------------------------------------------------------
__global__ __launch_bounds__(256, 3) void proj_kernel(
        const float* __restrict__ x, const bf16* __restrict__ Wt,
        bf16* __restrict__ qkv, bf16* __restrict__ Vt) {
    // smem: Abuf[2] f32 128x32 (16KB each) | Bbuf[2] bf16 128x32 (8KB each) = 48KB
    // Tl (34.8KB, w==2 epilogue) unioned on top.
    __shared__ __align__(16) char smem[49152];

    const int tid = threadIdx.x;
    const int lane = tid & 63;
    const int wave = tid >> 6;
    const int wr = wave >> 1, wc = wave & 1;
    const int r16 = lane & 15, kg = lane >> 4;
    const int mb = blockIdx.x;
    const int w = blockIdx.y;
    const float* xA = x + (size_t)mb * 128 * NDM;
    const bf16* Bt = Wt + (size_t)w * NDK * NDM;

    auto ABUF = [&](int b) -> float* { return (float*)(smem + b * 16384); };
    auto BBUF = [&](int b) -> bf16*  { return (bf16*)(smem + 32768 + b * 8192); };
    bf16 (*Tl)[136] = reinterpret_cast<bf16(*)[136]>(smem);

    // staging coords (constant per thread)
    // A: 1024 chunks of 16B (4 f32); 4 rounds. row=C>>3, c=C&7, src c^=(row&7)
    const int a_row = wave * 8 + (lane >> 3);      // + p*32
    const int a_c = lane & 7;
    // B: 512 chunks of 16B (8 bf16); 2 rounds. row=C>>2, c=C&3, src c^=((row>>1)&3)
    const int b_row = wave * 16 + (lane >> 2);     // + p*64
    const int b_c = lane & 3;

    auto stage = [&](int buf, int k0) {
#pragma unroll
        for (int p = 0; p < 4; p++) {
            int row = p * 32 + a_row;
            int csrc = a_c ^ (row & 7);
            gload_lds16(xA + (size_t)row * NDM + k0 + csrc * 4,
                        ABUF(buf) + (p * 256 + wave * 64) * 4);
        }
#pragma unroll
        for (int p = 0; p < 2; p++) {
            int row = p * 64 + b_row;
            int csrc = b_c ^ ((row >> 1) & 3);
            gload_lds16(Bt + (size_t)row * NDM + k0 + csrc * 8,
                        BBUF(buf) + (p * 256 + wave * 64) * 8);
        }
    };

    f32x4 acc[4][4];
#pragma unroll
    for (int m = 0; m < 4; m++)
#pragma unroll
        for (int n = 0; n < 4; n++) acc[m][n] = (f32x4){0.f, 0.f, 0.f, 0.f};

    stage(0, 0);
    __syncthreads();

    for (int kt = 0; kt < NDM / 32; kt++) {
        const int cur = kt & 1;
        if (kt + 1 < NDM / 32) stage(1 - cur, (kt + 1) * 32);   // async, in flight

        const float* Ac = ABUF(cur);
        const bf16* Bc = BBUF(cur);
        bf16x8 af[4], bfr[4];
#pragma unroll
        for (int m = 0; m < 4; m++) {
            int arow = wr * 64 + m * 16 + r16;
            const float* ap = Ac + arow * 32;
            float4 lo = *reinterpret_cast<const float4*>(ap + (((kg * 2) ^ (arow & 7)) * 4));
            float4 hi = *reinterpret_cast<const float4*>(ap + (((kg * 2 + 1) ^ (arow & 7)) * 4));
            bf16x8 a;
            a[0] = to_bf16(lo.x); a[1] = to_bf16(lo.y); a[2] = to_bf16(lo.z); a[3] = to_bf16(lo.w);
            a[4] = to_bf16(hi.x); a[5] = to_bf16(hi.y); a[6] = to_bf16(hi.z); a[7] = to_bf16(hi.w);
            af[m] = a;
        }
#pragma unroll
        for (int n = 0; n < 4; n++) {
            int brow = wc * 64 + n * 16 + r16;
            bfr[n] = *reinterpret_cast<const bf16x8*>(
                Bc + brow * 32 + ((kg ^ ((brow >> 1) & 3)) * 8));
        }
#pragma unroll
        for (int m = 0; m < 4; m++)
#pragma unroll
            for (int n = 0; n < 4; n++)
                acc[m][n] = __builtin_amdgcn_mfma_f32_16x16x32_bf16(af[m], bfr[n], acc[m][n], 0, 0, 0);
        __syncthreads();   // drains stage loads; all waves done with buf[cur]
    }

    if (w < 2) {
        bf16* outw = qkv + (size_t)w * (size_t)(NB * NT) * NDK;
#pragma unroll
        for (int m = 0; m < 4; m++) {
            int rowb = mb * 128 + wr * 64 + m * 16 + kg * 4;
#pragma unroll
            for (int n = 0; n < 4; n++) {
                int col = wc * 64 + n * 16 + r16;
#pragma unroll
                for (int r = 0; r < 4; r++)
                    outw[(size_t)(rowb + r) * NDK + col] = to_bf16(acc[m][n][r]);
            }
        }
    } else {
        // V: restage transposed tile in LDS, then coalesced bf16x8 stores
#pragma unroll
        for (int m = 0; m < 4; m++) {
            int tl = wr * 64 + m * 16 + kg * 4;
#pragma unroll
            for (int n = 0; n < 4; n++) {
                int d = wc * 64 + n * 16 + r16;
                bf16x4 pv = { to_bf16(acc[m][n][0]), to_bf16(acc[m][n][1]),
                              to_bf16(acc[m][n][2]), to_bf16(acc[m][n][3]) };
                *reinterpret_cast<bf16x4*>(&Tl[d][tl]) = pv;
            }
        }
        __syncthreads();
        const int b = mb >> 4;
        const int t0 = (mb & 15) * 128;
        bf16* Vb = Vt + (size_t)b * NDK * NT;
#pragma unroll
        for (int p = 0; p < 8; p++) {
            int idx = p * 256 + tid;         // 2048 chunks: 128 d-rows x 16
            int d = idx >> 4, c = idx & 15;
            *reinterpret_cast<bf16x8*>(&Vb[(size_t)d * NT + t0 + c * 8]) =
                *reinterpret_cast<const bf16x8*>(&Tl[d][c * 8]);
        }
    }
}

// ---------------------------------------------------------------------------
// Kernel 3: causal flash attention, swapped-QK^T softmax (S^T = K·Q^T so each
// lane owns one q-row's kv-slice -> in-lane reductions). K/V LDS double-
// buffered, one barrier per step, reg-prefetch 1 tile ahead (T14).
// ---------------------------------------------------------------------------
__global__ __launch_bounds__(256) void attn_kernel(
        const bf16* __restrict__ Q, const bf16* __restrict__ K,
        const bf16* __restrict__ Vt, float* __restrict__ out) {
    __shared__ bf16 Ks[2][64][128];   // [buf][kv][k], swizzled
    __shared__ bf16 Vs[2][128][64];   // [buf][d][kv], swizzled
    __shared__ bf16 Ps[4][16][72];    // [wave][q-local][kv], padded
    const int tid = threadIdx.x, lane = tid & 63, wave = tid >> 6;
    const int r16 = lane & 15, kg = lane >> 4;

    // XCD-aware mapping: each XCD owns 2 batches (KV working set 2MB < L2)
    const int bid = blockIdx.x;
    const int xcd = bid & 7;
    const int j = bid >> 3;
    const int b = xcd * 2 + (j & 1);
    const int qb = (NT / 64 - 1) - (j >> 1);   // longest first
    const int q0 = qb * 64;
    const size_t baseB = (size_t)b * NT * NDK;
    const size_t baseVt = (size_t)b * NDK * NT;

    const float scale = 0.08838834764831843f;  // 1/sqrt(128)
    bf16x8 qf[4];
    const int qglob = q0 + wave * 16 + r16;    // this lane's q-row
#pragma unroll
    for (int kc = 0; kc < 4; kc++) {
        bf16x8 raw = *reinterpret_cast<const bf16x8*>(&Q[baseB + (size_t)qglob * NDK + kc * 32 + kg * 8]);
#pragma unroll
        for (int jj = 0; jj < 8; jj++) raw[jj] = to_bf16((float)raw[jj] * scale);
        qf[kc] = raw;
    }

    f32x4 o[8];
#pragma unroll
    for (int n = 0; n < 8; n++) o[n] = (f32x4){0.f, 0.f, 0.f, 0.f};
    float mrun = -INFINITY;   // running max for q = qglob
    float lrun = 0.f;         // running denom

    int krow[4], kcol[4], vrow[4], vcol[4];
#pragma unroll
    for (int i = 0; i < 4; i++) {
        int idx = i * 256 + tid;
        krow[i] = idx >> 4; kcol[i] = idx & 15;   // 64 rows x 16 chunks
        vrow[i] = idx >> 3; vcol[i] = idx & 7;    // 128 rows x 8 chunks
    }

    const int nsteps = qb + 1;
    bf16x8 kreg[4], vreg[4];
    // prologue: tile 0 -> regs -> buf0; issue tile 1 loads
#pragma unroll
    for (int i = 0; i < 4; i++) {
        kreg[i] = *reinterpret_cast<const bf16x8*>(&K[baseB + (size_t)krow[i] * NDK + kcol[i] * 8]);
        vreg[i] = *reinterpret_cast<const bf16x8*>(&Vt[baseVt + (size_t)vrow[i] * NT + vcol[i] * 8]);
    }
#pragma unroll
    for (int i = 0; i < 4; i++) {
        *reinterpret_cast<bf16x8*>(&Ks[0][krow[i]][(kcol[i] ^ (krow[i] & 7)) * 8]) = kreg[i];
        *reinterpret_cast<bf16x8*>(&Vs[0][vrow[i]][(vcol[i] ^ (vrow[i] & 7)) * 8]) = vreg[i];
    }
    if (nsteps > 1) {
#pragma unroll
        for (int i = 0; i < 4; i++) {
            kreg[i] = *reinterpret_cast<const bf16x8*>(&K[baseB + (size_t)(64 + krow[i]) * NDK + kcol[i] * 8]);
            vreg[i] = *reinterpret_cast<const bf16x8*>(&Vt[baseVt + (size_t)vrow[i] * NT + 64 + vcol[i] * 8]);
        }
    }
    __syncthreads();

    for (int s = 0; s < nsteps; s++) {
        const int cur = s & 1;
        const int kv0 = s * 64;

        // S^T = K Q^T : D[kv][q], q = r16 (lane-local row), kv = n*16+kg*4+r
        f32x4 sfr[4];
#pragma unroll
        for (int n = 0; n < 4; n++) sfr[n] = (f32x4){0.f, 0.f, 0.f, 0.f};
#pragma unroll
        for (int n = 0; n < 4; n++) {
            const int krw = n * 16 + r16;
#pragma unroll
            for (int kc = 0; kc < 4; kc++) {
                bf16x8 kf = *reinterpret_cast<const bf16x8*>(&Ks[cur][krw][((kc * 4 + kg) ^ (krw & 7)) * 8]);
                sfr[n] = __builtin_amdgcn_mfma_f32_16x16x32_bf16(kf, qf[kc], sfr[n], 0, 0, 0);
            }
        }

        // causal mask only on diagonal tile: kv > q
        if (s == nsteps - 1) {
#pragma unroll
            for (int n = 0; n < 4; n++)
#pragma unroll
                for (int r = 0; r < 4; r++)
                    if (kv0 + n * 16 + kg * 4 + r > qglob) sfr[n][r] = -INFINITY;
        }

        // tile max: 15 in-lane + 2 cross-kg shuffles
        float pm = -INFINITY;
#pragma unroll
        for (int n = 0; n < 4; n++) {
            float t0 = fmaxf(fmaxf(sfr[n][0], sfr[n][1]), fmaxf(sfr[n][2], sfr[n][3]));
            pm = fmaxf(pm, t0);
        }
        pm = fmaxf(pm, __shfl_xor(pm, 16, 64));
        pm = fmaxf(pm, __shfl_xor(pm, 32, 64));

        // rescale O only if running max grew
        if (__any(pm > mrun)) {
            float mnew = fmaxf(mrun, pm);
            float corr = __expf(mrun - mnew);
            mrun = mnew;
            lrun *= corr;
            float co[4];
#pragma unroll
            for (int r = 0; r < 4; r++) co[r] = __shfl(corr, kg * 4 + r, 64);
#pragma unroll
            for (int n = 0; n < 8; n++)
#pragma unroll
                for (int r = 0; r < 4; r++) o[n][r] *= co[r];
        }

        // P = exp(S - m): in-lane sum, pack 4 bf16 per ds_write_b64
        float ps = 0.f;
#pragma unroll
        for (int n = 0; n < 4; n++) {
            bf16x4 pw;
#pragma unroll
            for (int r = 0; r < 4; r++) {
                float pv = __expf(sfr[n][r] - mrun);
                ps += pv;
                pw[r] = to_bf16(pv);
            }
            *reinterpret_cast<bf16x4*>(&Ps[wave][r16][n * 16 + kg * 4]) = pw;
        }
        ps += __shfl_xor(ps, 16, 64);
        ps += __shfl_xor(ps, 32, 64);
        lrun += ps;

        // O += P V
#pragma unroll
        for (int kc2 = 0; kc2 < 2; kc2++) {
            bf16x8 pf = *reinterpret_cast<const bf16x8*>(&Ps[wave][r16][kc2 * 32 + kg * 8]);
#pragma unroll
            for (int n = 0; n < 8; n++) {
                const int vrw = n * 16 + r16;
                bf16x8 vf = *reinterpret_cast<const bf16x8*>(&Vs[cur][vrw][((kc2 * 4 + kg) ^ (vrw & 7)) * 8]);
                o[n] = __builtin_amdgcn_mfma_f32_16x16x32_bf16(pf, vf, o[n], 0, 0, 0);
            }
        }

        // stage tile s+1 into the other buffer; issue loads for s+2
        if (s + 1 < nsteps) {
#pragma unroll
            for (int i = 0; i < 4; i++) {
                *reinterpret_cast<bf16x8*>(&Ks[1 - cur][krow[i]][(kcol[i] ^ (krow[i] & 7)) * 8]) = kreg[i];
                *reinterpret_cast<bf16x8*>(&Vs[1 - cur][vrow[i]][(vcol[i] ^ (vrow[i] & 7)) * 8]) = vreg[i];
            }
            if (s + 2 < nsteps) {
                const int kv2 = (s + 2) * 64;
#pragma unroll
                for (int i = 0; i < 4; i++) {
                    kreg[i] = *reinterpret_cast<const bf16x8*>(&K[baseB + (size_t)(kv2 + krow[i]) * NDK + kcol[i] * 8]);
                    vreg[i] = *reinterpret_cast<const bf16x8*>(&Vt[baseVt + (size_t)vrow[i] * NT + kv2 + vcol[i] * 8]);
                }
            }
        }
        __syncthreads();
    }

    float linv = 1.0f / lrun;
    float li[4];
#pragma unroll
    for (int r = 0; r < 4; r++) li[r] = __shfl(linv, kg * 4 + r, 64);
#pragma unroll
    for (int n = 0; n < 8; n++)
#pragma unroll
        for (int r = 0; r < 4; r++) {
            int row = q0 + wave * 16 + kg * 4 + r;
            int col = n * 16 + r16;
            out[baseB + (size_t)row * NDK + col] = o[n][r] * li[r];
        }
}

// ---------------------------------------------------------------------------
extern "C" void kernel_launch(void* const* d_in, const int* in_sizes, int n_in,
                              void* d_out, int out_size, void* d_ws, size_t ws_size,
                              hipStream_t stream) {
    const float* x  = (const float*)d_in[0];
    const float* Wq = (const float*)d_in[1];
    const float* Wk = (const float*)d_in[2];
    const float* Wv = (const float*)d_in[3];
    float* out = (float*)d_out;

    char* ws = (char*)d_ws;
    bf16* Wt  = (bf16*)ws;                        // 3*128*1024*2  = 768 KB
    bf16* qkv = (bf16*)(ws + (1ull << 20));       // Q,K planes: 16 MB
    bf16* Vtg = (bf16*)(ws + (26ull << 20));      // V^T [B][128][T]: 8 MB

    // 1) transpose weights to bf16 [3][128][1024]
    transpose_w_kernel<<<(3 * NDM * NDK) / 256, 256, 0, stream>>>(Wq, Wk, Wv, Wt);

    // 2) QKV projection (pipelined global_load_lds K-loop; V written transposed)
    dim3 g1((NB * NT) / 128, 3);
    proj_kernel<<<g1, 256, 0, stream>>>(x, Wt, qkv, Vtg);

    bf16* Qp = qkv;
    bf16* Kp = qkv + (size_t)(NB * NT) * NDK;

    // 3) causal flash attention (1-D grid, XCD-aware mapping inside)
    attn_kernel<<<dim3((NT / 64) * NB), 256, 0, stream>>>(Qp, Kp, Vtg, out);
}